// Round 18
// baseline (203.870 us; speedup 1.0000x reference)
//
#include <hip/hip_runtime.h>
#include <stdint.h>

#define Bb 4
#define Ss 2048
#define Dd 1024
#define Hh 16
#define DKk 64
#define Mm (Bb * Ss)  // 8192

typedef __attribute__((ext_vector_type(4))) float f32x4;
typedef __attribute__((ext_vector_type(16))) float f32x16;
typedef __attribute__((ext_vector_type(4))) float f4v;
typedef __attribute__((ext_vector_type(8))) unsigned short us8;
typedef __attribute__((ext_vector_type(4))) unsigned short us4;
typedef __attribute__((ext_vector_type(8))) __bf16 bf16x8;

__device__ __forceinline__ unsigned short bfbits(__bf16 x) {
  union { __bf16 b; unsigned short u; } v; v.b = x; return v.u;
}
__device__ __forceinline__ uint32_t packbf(float lo, float hi) {
  union { __bf16 b[2]; uint32_t u; } v;
  v.b[0] = (__bf16)lo; v.b[1] = (__bf16)hi;
  return v.u;
}
// v_permlane32_swap_b32: a[32:63] <-> b[0:31]  (in-place, both operands)
__device__ __forceinline__ void plswap(uint32_t& a, uint32_t& b) {
  asm("v_permlane32_swap_b32 %0, %1" : "+v"(a), "+v"(b));
}
// async global->LDS, 16B per lane; LDS dest = wave-uniform base + lane*16
__device__ __forceinline__ void gl16(const unsigned short* g, unsigned short* l) {
  __builtin_amdgcn_global_load_lds(
      (__attribute__((address_space(1))) void*)(g),
      (__attribute__((address_space(3))) void*)(l), 16, 0, 0);
}

// ---------------- weight prep: 4 plain bf16 cvts in one launch ----------------
__global__ __launch_bounds__(256)
void wprep(const float* __restrict__ Wq, unsigned short* __restrict__ oq,
           const float* __restrict__ Wk, unsigned short* __restrict__ ok,
           const float* __restrict__ Wv, unsigned short* __restrict__ ov,
           const float* __restrict__ Wo, unsigned short* __restrict__ oo,
           int n4) {
  int i = blockIdx.x * 256 + threadIdx.x;
  if (i >= n4) return;
  int w = blockIdx.y;
  const float* x = (w == 0) ? Wq : (w == 1) ? Wk : (w == 2) ? Wv : Wo;
  unsigned short* o = (w == 0) ? oq : (w == 1) ? ok : (w == 2) ? ov : oo;
  f4v v = *(const f4v*)(x + (size_t)i * 4);
  us4 h;
#pragma unroll
  for (int j = 0; j < 4; ++j) h[j] = bfbits((__bf16)v[j]);
  *(us4*)(o + (size_t)i * 4) = h;
}

// ---------------- fused Q+K+V projection GEMM (reads f32 activations) ------
// Three independent 512-block GEMMs in one 1536-block launch. XCD swizzle:
// op = slot/64 so each XCD runs its Q blocks, then K, then V -> weight panel
// L2-hot per phase. m97 body: 128x128, BK=64, XOR-swizzled ds_read_b128.
// A is staged FROM F32 with in-register bf16 conversion; the f32 loads for
// step k+1 are issued AFTER the second barrier (T14 async-STAGE split) so
// their HBM latency hides under compute(k). B (bf16 weights) stays gl16.
// op==2 (V) writes transposed VT[B,D,S] via the dead staging LDS.
__global__ __launch_bounds__(256)
void gemm_qkv(const float* __restrict__ Aq, const float* __restrict__ Ak,
              const float* __restrict__ Av,
              const unsigned short* __restrict__ Wqh, const unsigned short* __restrict__ Wkh,
              const unsigned short* __restrict__ Wvh,
              const float* __restrict__ bq, const float* __restrict__ bk,
              const float* __restrict__ bv,
              unsigned short* __restrict__ Qb, unsigned short* __restrict__ Kb,
              unsigned short* __restrict__ VT, float qscale) {
  __shared__ unsigned short S[2 * 128 * 64];   // staging; V reuses as T[128][68]
  unsigned short* Ath = S;
  unsigned short* Bth = S + 8192;

  const int tid = threadIdx.x;
  const int wave = tid >> 6, lane = tid & 63, g = lane >> 4, ln = lane & 15;
  const int wr = wave >> 1, wc = wave & 1;
  int dd = blockIdx.x;
  const int slot = dd >> 3;
  const int op = slot >> 6;                       // 0=Q 1=K 2=V (phase per XCD)
  const int orig = (dd & 7) * 64 + (slot & 63);   // within-op XCD swizzle
  const int bm = (orig >> 3) * 128;
  const int bn = (orig & 7) * 128;

  const float* Af          = (op == 0) ? Aq : (op == 1) ? Ak : Av;
  const unsigned short* Bh = (op == 0) ? Wqh : (op == 1) ? Wkh : Wvh;
  const float* bias        = (op == 0) ? bq : (op == 1) ? bk : bv;
  const float scale        = (op == 0) ? qscale : 1.0f;

  const int srow = lane >> 3;
  const int schunk = (lane & 7) ^ srow;

  f32x4 acc[4][4] = {};

  // per-thread A source (row/chunk fixed per unit u)
  const float* asrc[4];
#pragma unroll
  for (int u = 0; u < 4; ++u) {
    int flat = u * 256 + tid;
    int r = flat >> 3, gc = flat & 7;
    asrc[u] = Af + (size_t)(bm + r) * Dd + gc * 8;
  }

  f4v alo[4], ahi[4];
  // prologue: issue A(k=0) loads
#pragma unroll
  for (int u = 0; u < 4; ++u) {
    alo[u] = *(const f4v*)(asrc[u]);
    ahi[u] = *(const f4v*)(asrc[u] + 4);
  }

  for (int k0 = 0; k0 < Dd; k0 += 64) {
    __syncthreads();   // drains prefetched A loads; everyone done reading LDS
    // A(k): cvt + swizzled ds_write_b128 (LDS chunk gc^(r&7) holds global gc)
#pragma unroll
    for (int u = 0; u < 4; ++u) {
      int flat = u * 256 + tid;
      int r = flat >> 3, gc = flat & 7;
      us8 w;
#pragma unroll
      for (int j = 0; j < 4; ++j) {
        w[j]     = bfbits((__bf16)alo[u][j]);
        w[j + 4] = bfbits((__bf16)ahi[u][j]);
      }
      *(us8*)&Ath[r * 64 + ((gc ^ (r & 7)) * 8)] = w;
    }
    // B: async gl16 (pre-swizzled source, linear LDS dest)
#pragma unroll
    for (int ii = 0; ii < 4; ++ii) {
      const int rB = wave * 32 + ii * 8;
      gl16(&Bh[(size_t)(bn + rB + srow) * Dd + k0 + schunk * 8], &Bth[rB * 64]);
    }
    __syncthreads();   // drains gl16 B(k) + lgkm(ds_write A)

    // T14: issue A(k+1) loads NOW — in flight across compute(k)
    if (k0 + 64 < Dd) {
#pragma unroll
      for (int u = 0; u < 4; ++u) {
        alo[u] = *(const f4v*)(asrc[u] + k0 + 64);
        ahi[u] = *(const f4v*)(asrc[u] + k0 + 68);
      }
    }

#pragma unroll
    for (int ko = 0; ko < 2; ++ko) {
      bf16x8 ah[4], bh[4];
#pragma unroll
      for (int i = 0; i < 4; ++i) {
        const int ra = wr * 64 + i * 16 + ln;
        const int rb = wc * 64 + i * 16 + ln;
        ah[i] = *(const bf16x8*)&Ath[ra * 64 + ((ko * 4 + g) ^ (ra & 7)) * 8];
        bh[i] = *(const bf16x8*)&Bth[rb * 64 + ((ko * 4 + g) ^ (rb & 7)) * 8];
      }
#pragma unroll
      for (int i = 0; i < 4; ++i)
#pragma unroll
        for (int j = 0; j < 4; ++j)
          acc[i][j] = __builtin_amdgcn_mfma_f32_16x16x32_bf16(ah[i], bh[j], acc[i][j], 0, 0, 0);
    }
  }

  float bvals[4];
#pragma unroll
  for (int j = 0; j < 4; ++j) bvals[j] = bias[bn + wc * 64 + j * 16 + ln];

  if (op < 2) {
    unsigned short* outp = op ? Kb : Qb;
#pragma unroll
    for (int i = 0; i < 4; ++i) {
      int row0 = bm + wr * 64 + i * 16 + g * 4;
#pragma unroll
      for (int j = 0; j < 4; ++j) {
        int col = bn + wc * 64 + j * 16 + ln;
#pragma unroll
        for (int r = 0; r < 4; ++r) {
          float vv = (acc[i][j][r] + bvals[j]) * scale;
          outp[(size_t)(row0 + r) * Dd + col] = bfbits((__bf16)vv);
        }
      }
    }
    return;
  }

  // ---- op == 2: transposed output VT[b][d][s], two 64-s passes ----
  const int bb = bm >> 11, s0g = bm & 2047;
  __syncthreads();   // staging dead
#pragma unroll
  for (int p = 0; p < 2; ++p) {
    if (wr == p) {
#pragma unroll
      for (int i = 0; i < 4; ++i) {
        int sl0 = i * 16 + g * 4;
#pragma unroll
        for (int j = 0; j < 4; ++j) {
          int dl = wc * 64 + j * 16 + ln;
          us4 w;
#pragma unroll
          for (int r = 0; r < 4; ++r) w[r] = bfbits((__bf16)(acc[i][j][r] + bvals[j]));
          *(us4*)&S[dl * 68 + sl0] = w;
        }
      }
    }
    __syncthreads();
#pragma unroll
    for (int it = 0; it < 4; ++it) {
      int u = it * 256 + tid;
      int dl = u >> 3, sc = (u & 7) * 8;
      us8 o = *(const us8*)&S[dl * 68 + sc];
      *(us8*)&VT[((size_t)bb * Dd + bn + dl) * Ss + s0g + p * 64 + sc] = o;
    }
    __syncthreads();
  }
}

// ---------------- GEMM (Wo) v2: double-buffered, ONE barrier per K-step ----
// 128x128 tile, BK=64, LDS 64KB (2 bufs x A+B). stage(k+1) issued right
// after the barrier -> gl16 latency rides across compute(k); the next
// iteration's barrier (vmcnt(0) drain) is the wait point. fp32 out + bias.
__global__ __launch_bounds__(256)
void gemm_out(const unsigned short* __restrict__ A,
              const unsigned short* __restrict__ Bh,
              const float* __restrict__ bias, float* __restrict__ outp) {
  __shared__ unsigned short Ath[2][128 * 64];
  __shared__ unsigned short Bth[2][128 * 64];

  const int tid = threadIdx.x;
  const int wave = tid >> 6, lane = tid & 63, g = lane >> 4, ln = lane & 15;
  const int wr = wave >> 1, wc = wave & 1;
  int dd = blockIdx.x;
  int orig = (dd & 7) * 64 + (dd >> 3);   // XCD swizzle (512 = 8 * 64)
  const int bm = (orig >> 3) * 128;
  const int bn = (orig & 7) * 128;

  const int srow = lane >> 3;
  const int schunk = (lane & 7) ^ srow;

  f32x4 acc[4][4] = {};

  auto stage = [&](int k0, int nb) {
#pragma unroll
    for (int ii = 0; ii < 4; ++ii) {
      const int rA = wave * 32 + ii * 8;
      gl16(&A [(size_t)(bm + rA + srow) * Dd + k0 + schunk * 8], &Ath[nb][rA * 64]);
      gl16(&Bh[(size_t)(bn + rA + srow) * Dd + k0 + schunk * 8], &Bth[nb][rA * 64]);
    }
  };

  stage(0, 0);

  for (int step = 0; step < 16; ++step) {
    const int cur = step & 1;
    __syncthreads();   // vmcnt(0) drain -> buf[cur] ready; done reading buf[1-cur]
    if (step + 1 < 16) stage((step + 1) * 64, 1 - cur);

#pragma unroll
    for (int ko = 0; ko < 2; ++ko) {
      bf16x8 ah[4], bh[4];
#pragma unroll
      for (int i = 0; i < 4; ++i) {
        const int ra = wr * 64 + i * 16 + ln;
        const int rb = wc * 64 + i * 16 + ln;
        ah[i] = *(const bf16x8*)&Ath[cur][ra * 64 + ((ko * 4 + g) ^ (ra & 7)) * 8];
        bh[i] = *(const bf16x8*)&Bth[cur][rb * 64 + ((ko * 4 + g) ^ (rb & 7)) * 8];
      }
#pragma unroll
      for (int i = 0; i < 4; ++i)
#pragma unroll
        for (int j = 0; j < 4; ++j)
          acc[i][j] = __builtin_amdgcn_mfma_f32_16x16x32_bf16(ah[i], bh[j], acc[i][j], 0, 0, 0);
    }
  }

  float bvals[4];
#pragma unroll
  for (int j = 0; j < 4; ++j) bvals[j] = bias[bn + wc * 64 + j * 16 + ln];

#pragma unroll
  for (int i = 0; i < 4; ++i) {
    int row0 = bm + wr * 64 + i * 16 + g * 4;
#pragma unroll
    for (int j = 0; j < 4; ++j) {
      int col = bn + wc * 64 + j * 16 + ln;
#pragma unroll
      for (int r = 0; r < 4; ++r)
        outp[(size_t)(row0 + r) * Dd + col] = acc[i][j][r] + bvals[j];
    }
  }
}

// ---------------- fused flash attention v5.1 (32x32x16 MFMA) ----------------
// QBLK=128, double-buffered gload_lds K/V, XOR swizzle, one barrier/tile,
// fixed-max softmax, native exp2, P in registers via permlane32_swap,
// l-sums on the MFMA pipe, incremented staging pointers.
__global__ __launch_bounds__(256, 4)
void attn_fused(const unsigned short* __restrict__ Qb, const unsigned short* __restrict__ Kb,
                const unsigned short* __restrict__ VT, unsigned short* __restrict__ xb) {
  __shared__ unsigned short Ks[2][64 * 64];
  __shared__ unsigned short Vs[2][64 * 64];   // V^T tile: [d][kv]

  const int tid = threadIdx.x, wave = tid >> 6, lane = tid & 63;
  const int lq = lane & 31, hi = lane >> 5;
  const int swzc = (lane & 7) ^ ((lane >> 3) & 7);  // pre-swizzled source chunk

  int dd = blockIdx.x;
  int orig = (dd & 7) * 128 + (dd >> 3);  // XCD swizzle (1024 = 8 * 128)
  const int bh = orig >> 4, qb = orig & 15;
  const int q0 = qb * 128;
  const int b = bh >> 4, h = bh & 15;

  const size_t rowBase = (size_t)b * Ss * Dd + (size_t)h * DKk;
  const size_t vtBase  = ((size_t)b * Dd + h * DKk) * Ss;

  // Q B-operand frags (once): lane holds Q[qrow][16c + 8hi + j]
  bf16x8 qf[4];
  {
    const unsigned short* qrow =
        Qb + rowBase + (size_t)(q0 + wave * 32 + lq) * Dd + 8 * hi;
#pragma unroll
    for (int c = 0; c < 4; ++c) qf[c] = *(const bf16x8*)(qrow + 16 * c);
  }

  // ones fragment for the l-row-sum MFMA
  bf16x8 ones;
#pragma unroll
  for (int j = 0; j < 8; ++j) ones[j] = (__bf16)1.0f;

  f32x16 accO[2] = {};   // [ds]
  f32x16 acc_l = {};     // row sums (replicated across cols)

  // staging pointers: advance by constant strides each tile (no mad64 chains)
  const int i0 = wave * 2;
  const int prow = i0 * 8 + (lane >> 3);
  const unsigned short* kp0 = Kb + rowBase + (size_t)prow * Dd + swzc * 8;
  const unsigned short* kp1 = kp0 + (size_t)8 * Dd;
  const unsigned short* vp0 = VT + vtBase + (size_t)prow * Ss + swzc * 8;
  const unsigned short* vp1 = vp0 + (size_t)8 * Ss;

  auto stage = [&](int nb) {
    gl16(kp0, &Ks[nb][(i0 + 0) * 512]);
    gl16(kp1, &Ks[nb][(i0 + 1) * 512]);
    gl16(vp0, &Vs[nb][(i0 + 0) * 512]);
    gl16(vp1, &Vs[nb][(i0 + 1) * 512]);
    kp0 += (size_t)64 * Dd; kp1 += (size_t)64 * Dd;
    vp0 += 64; vp1 += 64;
  };

  stage(0);

  for (int t = 0; t < 32; ++t) {
    const int cur = t & 1;
    __syncthreads();   // vmcnt(0) drain -> buf[cur] ready; all done reading buf[1-cur]
    if (t + 1 < 32) stage(1 - cur);

    uint32_t pf[4][4];   // [m][word] PV A-frags (all indices static)
#pragma unroll
    for (int s = 0; s < 2; ++s) {
      f32x16 z = {};
#pragma unroll
      for (int c = 0; c < 4; ++c) {
        bf16x8 kf = *(const bf16x8*)
            &Ks[cur][(s * 32 + lq) * 64 + ((2 * c + hi) ^ (lq & 7)) * 8];
        z = __builtin_amdgcn_mfma_f32_32x32x16_bf16(kf, qf[c], z, 0, 0, 0);
      }
      // native exp2 (Q pre-scaled by 0.125*log2e) + pack pairs
      uint32_t w[8];
#pragma unroll
      for (int i = 0; i < 8; ++i) {
        float e0 = __builtin_amdgcn_exp2f(z[2 * i]);
        float e1 = __builtin_amdgcn_exp2f(z[2 * i + 1]);
        w[i] = packbf(e0, e1);
      }
      // build PV A-frags m = 2s, 2s+1 via half-lane swaps
#pragma unroll
      for (int mm = 0; mm < 2; ++mm) {
        uint32_t a0 = w[4 * mm + 0], b0 = w[4 * mm + 2];
        uint32_t a1 = w[4 * mm + 1], b1 = w[4 * mm + 3];
        plswap(a0, b0);
        plswap(a1, b1);
        pf[2 * s + mm][0] = a0;
        pf[2 * s + mm][1] = a1;
        pf[2 * s + mm][2] = b0;
        pf[2 * s + mm][3] = b1;
      }
    }

    // PV + l row-sums: pure MFMA cluster
    __builtin_amdgcn_s_setprio(1);
#pragma unroll
    for (int m = 0; m < 4; ++m) {
      bf16x8 pa = *(const bf16x8*)&pf[m][0];
      acc_l = __builtin_amdgcn_mfma_f32_32x32x16_bf16(pa, ones, acc_l, 0, 0, 0);
#pragma unroll
      for (int ds = 0; ds < 2; ++ds) {
        bf16x8 bv = *(const bf16x8*)
            &Vs[cur][(ds * 32 + lq) * 64 + ((2 * m + hi) ^ (lq & 7)) * 8];
        accO[ds] = __builtin_amdgcn_mfma_f32_32x32x16_bf16(pa, bv, accO[ds], 0, 0, 0);
      }
    }
    __builtin_amdgcn_s_setprio(0);
  }

  // epilogue: acc_l rows align with accO rows (row = (r&3)+8*(r>>2)+4*hi)
#pragma unroll
  for (int ds = 0; ds < 2; ++ds)
#pragma unroll
    for (int r = 0; r < 16; ++r) {
      int q = (r & 3) + 8 * (r >> 2) + 4 * hi;
      size_t row = (size_t)b * Ss + q0 + wave * 32 + q;
      xb[row * Dd + h * DKk + ds * 32 + lq] =
          bfbits((__bf16)(accO[ds][r] / acc_l[r]));
    }
}

extern "C" void kernel_launch(void* const* d_in, const int* in_sizes, int n_in,
                              void* d_out, int out_size, void* d_ws, size_t ws_size,
                              hipStream_t stream) {
  const float* q  = (const float*)d_in[0];
  const float* k  = (const float*)d_in[1];
  const float* v  = (const float*)d_in[2];
  // d_in[3] = mask, faithfully ignored (reference discards masked_fill result)
  const float* Wq = (const float*)d_in[4];
  const float* bq = (const float*)d_in[5];
  const float* Wk = (const float*)d_in[6];
  const float* bk = (const float*)d_in[7];
  const float* Wv = (const float*)d_in[8];
  const float* bv = (const float*)d_in[9];
  const float* Wo = (const float*)d_in[10];
  const float* bo = (const float*)d_in[11];

  char* ws = (char*)d_ws;
  const size_t SZT = (size_t)Mm * Dd * 2;  // 16 MiB (one bf16 activation tensor)
  const size_t SZW = (size_t)Dd * Dd * 2;  // 2 MiB  (one bf16 weight tensor)
  const size_t need = 4 * SZT + 4 * SZW;   // ~72 MiB
  if (ws_size < need) return;  // fail loudly via poisoned output

  unsigned short* Wqh = (unsigned short*)(ws + 0 * SZW);
  unsigned short* Wkh = (unsigned short*)(ws + 1 * SZW);
  unsigned short* Wvh = (unsigned short*)(ws + 2 * SZW);
  unsigned short* Woh = (unsigned short*)(ws + 3 * SZW);
  char* base2 = ws + 4 * SZW;
  unsigned short* Qb  = (unsigned short*)(base2 + 0 * SZT);
  unsigned short* Kb  = (unsigned short*)(base2 + 1 * SZT);
  unsigned short* VTs = (unsigned short*)(base2 + 2 * SZT);
  unsigned short* xbp = (unsigned short*)(base2 + 3 * SZT);

  const int n4w = Dd * Dd / 4;  // 262,144
  const float QSCALE = 0.125f * 1.44269504f;  // 1/sqrt(d_k) * log2(e)

  // weight prep: 4 plain bf16 cvts, one launch
  wprep<<<dim3(n4w / 256, 4), 256, 0, stream>>>(Wq, Wqh, Wk, Wkh, Wv, Wvh, Wo, Woh, n4w);

  // fused Q+K+V projections reading f32 activations directly
  // (Q pre-scaled by 0.125*log2e; V written transposed to VT)
  gemm_qkv<<<1536, 256, 0, stream>>>(q, k, v, Wqh, Wkh, Wvh,
                                     bq, bk, bv, Qb, Kb, VTs, QSCALE);

  // fused attention -> x (bf16)
  attn_fused<<<1024, 256, 0, stream>>>(Qb, Kb, VTs, xbp);

  // output projection (double-buffered, one barrier/K-step), fp32 out + bias
  gemm_out<<<512, 256, 0, stream>>>(xbp, Woh, bo, (float*)d_out);
}

// Round 19
// 199.617 us; speedup vs baseline: 1.0213x; 1.0213x over previous
//
#include <hip/hip_runtime.h>
#include <stdint.h>

#define Bb 4
#define Ss 2048
#define Dd 1024
#define Hh 16
#define DKk 64
#define Mm (Bb * Ss)  // 8192

typedef __attribute__((ext_vector_type(4))) float f32x4;
typedef __attribute__((ext_vector_type(16))) float f32x16;
typedef __attribute__((ext_vector_type(4))) float f4v;
typedef __attribute__((ext_vector_type(8))) unsigned short us8;
typedef __attribute__((ext_vector_type(4))) unsigned short us4;
typedef __attribute__((ext_vector_type(8))) __bf16 bf16x8;

__device__ __forceinline__ unsigned short bfbits(__bf16 x) {
  union { __bf16 b; unsigned short u; } v; v.b = x; return v.u;
}
__device__ __forceinline__ uint32_t packbf(float lo, float hi) {
  union { __bf16 b[2]; uint32_t u; } v;
  v.b[0] = (__bf16)lo; v.b[1] = (__bf16)hi;
  return v.u;
}
// v_permlane32_swap_b32: a[32:63] <-> b[0:31]  (in-place, both operands)
__device__ __forceinline__ void plswap(uint32_t& a, uint32_t& b) {
  asm("v_permlane32_swap_b32 %0, %1" : "+v"(a), "+v"(b));
}
// async global->LDS, 16B per lane; LDS dest = wave-uniform base + lane*16
__device__ __forceinline__ void gl16(const unsigned short* g, unsigned short* l) {
  __builtin_amdgcn_global_load_lds(
      (__attribute__((address_space(1))) void*)(g),
      (__attribute__((address_space(3))) void*)(l), 16, 0, 0);
}

// ---------------- weight prep: 4 plain bf16 cvts in one launch ----------------
__global__ __launch_bounds__(256)
void wprep(const float* __restrict__ Wq, unsigned short* __restrict__ oq,
           const float* __restrict__ Wk, unsigned short* __restrict__ ok,
           const float* __restrict__ Wv, unsigned short* __restrict__ ov,
           const float* __restrict__ Wo, unsigned short* __restrict__ oo,
           int n4) {
  int i = blockIdx.x * 256 + threadIdx.x;
  if (i >= n4) return;
  int w = blockIdx.y;
  const float* x = (w == 0) ? Wq : (w == 1) ? Wk : (w == 2) ? Wv : Wo;
  unsigned short* o = (w == 0) ? oq : (w == 1) ? ok : (w == 2) ? ov : oo;
  f4v v = *(const f4v*)(x + (size_t)i * 4);
  us4 h;
#pragma unroll
  for (int j = 0; j < 4; ++j) h[j] = bfbits((__bf16)v[j]);
  *(us4*)(o + (size_t)i * 4) = h;
}

// ---------------- fused Q+K+V projection GEMM (reads f32 activations) ------
// Three independent 512-block GEMMs in one 1536-block launch. XCD swizzle:
// op = slot/64 so each XCD runs its Q blocks, then K, then V -> weight panel
// L2-hot per phase. m97 body: 128x128, BK=64, XOR-swizzled ds_read_b128.
// A is staged FROM F32 with in-register bf16 conversion; the f32 loads for
// step k+1 are issued AFTER the second barrier (T14 async-STAGE split) so
// their HBM latency hides under compute(k). B (bf16 weights) stays gl16.
// op==2 (V) writes transposed VT[B,D,S] via the dead staging LDS.
__global__ __launch_bounds__(256)
void gemm_qkv(const float* __restrict__ Aq, const float* __restrict__ Ak,
              const float* __restrict__ Av,
              const unsigned short* __restrict__ Wqh, const unsigned short* __restrict__ Wkh,
              const unsigned short* __restrict__ Wvh,
              const float* __restrict__ bq, const float* __restrict__ bk,
              const float* __restrict__ bv,
              unsigned short* __restrict__ Qb, unsigned short* __restrict__ Kb,
              unsigned short* __restrict__ VT, float qscale) {
  __shared__ unsigned short S[2 * 128 * 64];   // staging; V reuses as T[128][68]
  unsigned short* Ath = S;
  unsigned short* Bth = S + 8192;

  const int tid = threadIdx.x;
  const int wave = tid >> 6, lane = tid & 63, g = lane >> 4, ln = lane & 15;
  const int wr = wave >> 1, wc = wave & 1;
  int dd = blockIdx.x;
  const int slot = dd >> 3;
  const int op = slot >> 6;                       // 0=Q 1=K 2=V (phase per XCD)
  const int orig = (dd & 7) * 64 + (slot & 63);   // within-op XCD swizzle
  const int bm = (orig >> 3) * 128;
  const int bn = (orig & 7) * 128;

  const float* Af          = (op == 0) ? Aq : (op == 1) ? Ak : Av;
  const unsigned short* Bh = (op == 0) ? Wqh : (op == 1) ? Wkh : Wvh;
  const float* bias        = (op == 0) ? bq : (op == 1) ? bk : bv;
  const float scale        = (op == 0) ? qscale : 1.0f;

  const int srow = lane >> 3;
  const int schunk = (lane & 7) ^ srow;

  f32x4 acc[4][4] = {};

  // per-thread A source (row/chunk fixed per unit u)
  const float* asrc[4];
#pragma unroll
  for (int u = 0; u < 4; ++u) {
    int flat = u * 256 + tid;
    int r = flat >> 3, gc = flat & 7;
    asrc[u] = Af + (size_t)(bm + r) * Dd + gc * 8;
  }

  f4v alo[4], ahi[4];
  // prologue: issue A(k=0) loads
#pragma unroll
  for (int u = 0; u < 4; ++u) {
    alo[u] = *(const f4v*)(asrc[u]);
    ahi[u] = *(const f4v*)(asrc[u] + 4);
  }

  for (int k0 = 0; k0 < Dd; k0 += 64) {
    __syncthreads();   // drains prefetched A loads; everyone done reading LDS
    // A(k): cvt + swizzled ds_write_b128 (LDS chunk gc^(r&7) holds global gc)
#pragma unroll
    for (int u = 0; u < 4; ++u) {
      int flat = u * 256 + tid;
      int r = flat >> 3, gc = flat & 7;
      us8 w;
#pragma unroll
      for (int j = 0; j < 4; ++j) {
        w[j]     = bfbits((__bf16)alo[u][j]);
        w[j + 4] = bfbits((__bf16)ahi[u][j]);
      }
      *(us8*)&Ath[r * 64 + ((gc ^ (r & 7)) * 8)] = w;
    }
    // B: async gl16 (pre-swizzled source, linear LDS dest)
#pragma unroll
    for (int ii = 0; ii < 4; ++ii) {
      const int rB = wave * 32 + ii * 8;
      gl16(&Bh[(size_t)(bn + rB + srow) * Dd + k0 + schunk * 8], &Bth[rB * 64]);
    }
    __syncthreads();   // drains gl16 B(k) + lgkm(ds_write A)

    // T14: issue A(k+1) loads NOW — in flight across compute(k)
    if (k0 + 64 < Dd) {
#pragma unroll
      for (int u = 0; u < 4; ++u) {
        alo[u] = *(const f4v*)(asrc[u] + k0 + 64);
        ahi[u] = *(const f4v*)(asrc[u] + k0 + 68);
      }
    }

#pragma unroll
    for (int ko = 0; ko < 2; ++ko) {
      bf16x8 ah[4], bh[4];
#pragma unroll
      for (int i = 0; i < 4; ++i) {
        const int ra = wr * 64 + i * 16 + ln;
        const int rb = wc * 64 + i * 16 + ln;
        ah[i] = *(const bf16x8*)&Ath[ra * 64 + ((ko * 4 + g) ^ (ra & 7)) * 8];
        bh[i] = *(const bf16x8*)&Bth[rb * 64 + ((ko * 4 + g) ^ (rb & 7)) * 8];
      }
#pragma unroll
      for (int i = 0; i < 4; ++i)
#pragma unroll
        for (int j = 0; j < 4; ++j)
          acc[i][j] = __builtin_amdgcn_mfma_f32_16x16x32_bf16(ah[i], bh[j], acc[i][j], 0, 0, 0);
    }
  }

  float bvals[4];
#pragma unroll
  for (int j = 0; j < 4; ++j) bvals[j] = bias[bn + wc * 64 + j * 16 + ln];

  if (op < 2) {
    unsigned short* outp = op ? Kb : Qb;
#pragma unroll
    for (int i = 0; i < 4; ++i) {
      int row0 = bm + wr * 64 + i * 16 + g * 4;
#pragma unroll
      for (int j = 0; j < 4; ++j) {
        int col = bn + wc * 64 + j * 16 + ln;
#pragma unroll
        for (int r = 0; r < 4; ++r) {
          float vv = (acc[i][j][r] + bvals[j]) * scale;
          outp[(size_t)(row0 + r) * Dd + col] = bfbits((__bf16)vv);
        }
      }
    }
    return;
  }

  // ---- op == 2: transposed output VT[b][d][s], two 64-s passes ----
  const int bb = bm >> 11, s0g = bm & 2047;
  __syncthreads();   // staging dead
#pragma unroll
  for (int p = 0; p < 2; ++p) {
    if (wr == p) {
#pragma unroll
      for (int i = 0; i < 4; ++i) {
        int sl0 = i * 16 + g * 4;
#pragma unroll
        for (int j = 0; j < 4; ++j) {
          int dl = wc * 64 + j * 16 + ln;
          us4 w;
#pragma unroll
          for (int r = 0; r < 4; ++r) w[r] = bfbits((__bf16)(acc[i][j][r] + bvals[j]));
          *(us4*)&S[dl * 68 + sl0] = w;
        }
      }
    }
    __syncthreads();
#pragma unroll
    for (int it = 0; it < 4; ++it) {
      int u = it * 256 + tid;
      int dl = u >> 3, sc = (u & 7) * 8;
      us8 o = *(const us8*)&S[dl * 68 + sc];
      *(us8*)&VT[((size_t)bb * Dd + bn + dl) * Ss + s0g + p * 64 + sc] = o;
    }
    __syncthreads();
  }
}

// ---------------- GEMM (Wo): 128x128 tile, fp32 out + bias ----------------
__global__ __launch_bounds__(256)
void gemm_out(const unsigned short* __restrict__ A,
              const unsigned short* __restrict__ Bh,
              const float* __restrict__ bias, float* __restrict__ outp) {
  __shared__ unsigned short Ath[128 * 64];
  __shared__ unsigned short Bth[128 * 64];

  const int tid = threadIdx.x;
  const int wave = tid >> 6, lane = tid & 63, g = lane >> 4, ln = lane & 15;
  const int wr = wave >> 1, wc = wave & 1;
  int dd = blockIdx.x;
  int orig = (dd & 7) * 64 + (dd >> 3);   // XCD swizzle (512 = 8 * 64)
  const int bm = (orig >> 3) * 128;
  const int bn = (orig & 7) * 128;

  const int srow = lane >> 3;
  const int schunk = (lane & 7) ^ srow;

  f32x4 acc[4][4] = {};

  for (int k0 = 0; k0 < Dd; k0 += 64) {
    __syncthreads();
#pragma unroll
    for (int ii = 0; ii < 4; ++ii) {
      const int rA = wave * 32 + ii * 8;
      gl16(&A [(size_t)(bm + rA + srow) * Dd + k0 + schunk * 8], &Ath[rA * 64]);
      gl16(&Bh[(size_t)(bn + rA + srow) * Dd + k0 + schunk * 8], &Bth[rA * 64]);
    }
    __syncthreads();

#pragma unroll
    for (int ko = 0; ko < 2; ++ko) {
      bf16x8 ah[4], bh[4];
#pragma unroll
      for (int i = 0; i < 4; ++i) {
        const int ra = wr * 64 + i * 16 + ln;
        const int rb = wc * 64 + i * 16 + ln;
        ah[i] = *(const bf16x8*)&Ath[ra * 64 + ((ko * 4 + g) ^ (ra & 7)) * 8];
        bh[i] = *(const bf16x8*)&Bth[rb * 64 + ((ko * 4 + g) ^ (rb & 7)) * 8];
      }
#pragma unroll
      for (int i = 0; i < 4; ++i)
#pragma unroll
        for (int j = 0; j < 4; ++j)
          acc[i][j] = __builtin_amdgcn_mfma_f32_16x16x32_bf16(ah[i], bh[j], acc[i][j], 0, 0, 0);
    }
  }

  float bvals[4];
#pragma unroll
  for (int j = 0; j < 4; ++j) bvals[j] = bias[bn + wc * 64 + j * 16 + ln];

#pragma unroll
  for (int i = 0; i < 4; ++i) {
    int row0 = bm + wr * 64 + i * 16 + g * 4;
#pragma unroll
    for (int j = 0; j < 4; ++j) {
      int col = bn + wc * 64 + j * 16 + ln;
#pragma unroll
      for (int r = 0; r < 4; ++r)
        outp[(size_t)(row0 + r) * Dd + col] = acc[i][j][r] + bvals[j];
    }
  }
}

// ---------------- fused flash attention v5.1 (32x32x16 MFMA) ----------------
// QBLK=128, double-buffered gload_lds K/V, XOR swizzle, one barrier/tile,
// fixed-max softmax, native exp2, P in registers via permlane32_swap,
// l-sums on the MFMA pipe, incremented staging pointers.
__global__ __launch_bounds__(256, 4)
void attn_fused(const unsigned short* __restrict__ Qb, const unsigned short* __restrict__ Kb,
                const unsigned short* __restrict__ VT, unsigned short* __restrict__ xb) {
  __shared__ unsigned short Ks[2][64 * 64];
  __shared__ unsigned short Vs[2][64 * 64];   // V^T tile: [d][kv]

  const int tid = threadIdx.x, wave = tid >> 6, lane = tid & 63;
  const int lq = lane & 31, hi = lane >> 5;
  const int swzc = (lane & 7) ^ ((lane >> 3) & 7);  // pre-swizzled source chunk

  int dd = blockIdx.x;
  int orig = (dd & 7) * 128 + (dd >> 3);  // XCD swizzle (1024 = 8 * 128)
  const int bh = orig >> 4, qb = orig & 15;
  const int q0 = qb * 128;
  const int b = bh >> 4, h = bh & 15;

  const size_t rowBase = (size_t)b * Ss * Dd + (size_t)h * DKk;
  const size_t vtBase  = ((size_t)b * Dd + h * DKk) * Ss;

  // Q B-operand frags (once): lane holds Q[qrow][16c + 8hi + j]
  bf16x8 qf[4];
  {
    const unsigned short* qrow =
        Qb + rowBase + (size_t)(q0 + wave * 32 + lq) * Dd + 8 * hi;
#pragma unroll
    for (int c = 0; c < 4; ++c) qf[c] = *(const bf16x8*)(qrow + 16 * c);
  }

  // ones fragment for the l-row-sum MFMA
  bf16x8 ones;
#pragma unroll
  for (int j = 0; j < 8; ++j) ones[j] = (__bf16)1.0f;

  f32x16 accO[2] = {};   // [ds]
  f32x16 acc_l = {};     // row sums (replicated across cols)

  // staging pointers: advance by constant strides each tile (no mad64 chains)
  const int i0 = wave * 2;
  const int prow = i0 * 8 + (lane >> 3);
  const unsigned short* kp0 = Kb + rowBase + (size_t)prow * Dd + swzc * 8;
  const unsigned short* kp1 = kp0 + (size_t)8 * Dd;
  const unsigned short* vp0 = VT + vtBase + (size_t)prow * Ss + swzc * 8;
  const unsigned short* vp1 = vp0 + (size_t)8 * Ss;

  auto stage = [&](int nb) {
    gl16(kp0, &Ks[nb][(i0 + 0) * 512]);
    gl16(kp1, &Ks[nb][(i0 + 1) * 512]);
    gl16(vp0, &Vs[nb][(i0 + 0) * 512]);
    gl16(vp1, &Vs[nb][(i0 + 1) * 512]);
    kp0 += (size_t)64 * Dd; kp1 += (size_t)64 * Dd;
    vp0 += 64; vp1 += 64;
  };

  stage(0);

  for (int t = 0; t < 32; ++t) {
    const int cur = t & 1;
    __syncthreads();   // vmcnt(0) drain -> buf[cur] ready; all done reading buf[1-cur]
    if (t + 1 < 32) stage(1 - cur);

    uint32_t pf[4][4];   // [m][word] PV A-frags (all indices static)
#pragma unroll
    for (int s = 0; s < 2; ++s) {
      f32x16 z = {};
#pragma unroll
      for (int c = 0; c < 4; ++c) {
        bf16x8 kf = *(const bf16x8*)
            &Ks[cur][(s * 32 + lq) * 64 + ((2 * c + hi) ^ (lq & 7)) * 8];
        z = __builtin_amdgcn_mfma_f32_32x32x16_bf16(kf, qf[c], z, 0, 0, 0);
      }
      // native exp2 (Q pre-scaled by 0.125*log2e) + pack pairs
      uint32_t w[8];
#pragma unroll
      for (int i = 0; i < 8; ++i) {
        float e0 = __builtin_amdgcn_exp2f(z[2 * i]);
        float e1 = __builtin_amdgcn_exp2f(z[2 * i + 1]);
        w[i] = packbf(e0, e1);
      }
      // build PV A-frags m = 2s, 2s+1 via half-lane swaps
#pragma unroll
      for (int mm = 0; mm < 2; ++mm) {
        uint32_t a0 = w[4 * mm + 0], b0 = w[4 * mm + 2];
        uint32_t a1 = w[4 * mm + 1], b1 = w[4 * mm + 3];
        plswap(a0, b0);
        plswap(a1, b1);
        pf[2 * s + mm][0] = a0;
        pf[2 * s + mm][1] = a1;
        pf[2 * s + mm][2] = b0;
        pf[2 * s + mm][3] = b1;
      }
    }

    // PV + l row-sums: pure MFMA cluster
    __builtin_amdgcn_s_setprio(1);
#pragma unroll
    for (int m = 0; m < 4; ++m) {
      bf16x8 pa = *(const bf16x8*)&pf[m][0];
      acc_l = __builtin_amdgcn_mfma_f32_32x32x16_bf16(pa, ones, acc_l, 0, 0, 0);
#pragma unroll
      for (int ds = 0; ds < 2; ++ds) {
        bf16x8 bv = *(const bf16x8*)
            &Vs[cur][(ds * 32 + lq) * 64 + ((2 * m + hi) ^ (lq & 7)) * 8];
        accO[ds] = __builtin_amdgcn_mfma_f32_32x32x16_bf16(pa, bv, accO[ds], 0, 0, 0);
      }
    }
    __builtin_amdgcn_s_setprio(0);
  }

  // epilogue: acc_l rows align with accO rows (row = (r&3)+8*(r>>2)+4*hi)
#pragma unroll
  for (int ds = 0; ds < 2; ++ds)
#pragma unroll
    for (int r = 0; r < 16; ++r) {
      int q = (r & 3) + 8 * (r >> 2) + 4 * hi;
      size_t row = (size_t)b * Ss + q0 + wave * 32 + q;
      xb[row * Dd + h * DKk + ds * 32 + lq] =
          bfbits((__bf16)(accO[ds][r] / acc_l[r]));
    }
}

extern "C" void kernel_launch(void* const* d_in, const int* in_sizes, int n_in,
                              void* d_out, int out_size, void* d_ws, size_t ws_size,
                              hipStream_t stream) {
  const float* q  = (const float*)d_in[0];
  const float* k  = (const float*)d_in[1];
  const float* v  = (const float*)d_in[2];
  // d_in[3] = mask, faithfully ignored (reference discards masked_fill result)
  const float* Wq = (const float*)d_in[4];
  const float* bq = (const float*)d_in[5];
  const float* Wk = (const float*)d_in[6];
  const float* bk = (const float*)d_in[7];
  const float* Wv = (const float*)d_in[8];
  const float* bv = (const float*)d_in[9];
  const float* Wo = (const float*)d_in[10];
  const float* bo = (const float*)d_in[11];

  char* ws = (char*)d_ws;
  const size_t SZT = (size_t)Mm * Dd * 2;  // 16 MiB (one bf16 activation tensor)
  const size_t SZW = (size_t)Dd * Dd * 2;  // 2 MiB  (one bf16 weight tensor)
  const size_t need = 4 * SZT + 4 * SZW;   // ~72 MiB
  if (ws_size < need) return;  // fail loudly via poisoned output

  unsigned short* Wqh = (unsigned short*)(ws + 0 * SZW);
  unsigned short* Wkh = (unsigned short*)(ws + 1 * SZW);
  unsigned short* Wvh = (unsigned short*)(ws + 2 * SZW);
  unsigned short* Woh = (unsigned short*)(ws + 3 * SZW);
  char* base2 = ws + 4 * SZW;
  unsigned short* Qb  = (unsigned short*)(base2 + 0 * SZT);
  unsigned short* Kb  = (unsigned short*)(base2 + 1 * SZT);
  unsigned short* VTs = (unsigned short*)(base2 + 2 * SZT);
  unsigned short* xbp = (unsigned short*)(base2 + 3 * SZT);

  const int n4w = Dd * Dd / 4;  // 262,144
  const float QSCALE = 0.125f * 1.44269504f;  // 1/sqrt(d_k) * log2(e)

  // weight prep: 4 plain bf16 cvts, one launch
  wprep<<<dim3(n4w / 256, 4), 256, 0, stream>>>(Wq, Wqh, Wk, Wkh, Wv, Wvh, Wo, Woh, n4w);

  // fused Q+K+V projections reading f32 activations directly
  // (Q pre-scaled by 0.125*log2e; V written transposed to VT)
  gemm_qkv<<<1536, 256, 0, stream>>>(q, k, v, Wqh, Wkh, Wvh,
                                     bq, bk, bv, Qb, Kb, VTs, QSCALE);

  // fused attention -> x (bf16)
  attn_fused<<<1024, 256, 0, stream>>>(Qb, Kb, VTs, xbp);

  // output projection (128x128 tile, 512 blocks), fp32 out + bias
  gemm_out<<<512, 256, 0, stream>>>(xbp, Woh, bo, (float*)d_out);
}